// Round 13
// baseline (380.422 us; speedup 1.0000x reference)
//
#include <hip/hip_runtime.h>
#include <hip/hip_bf16.h>

// ---------------- problem constants ----------------
#define NTT 128
#define NXX 512
#define NB  2
#define NPN (NTT*NXX)        // 65536 nodes per batch
#define NNODES (NB*NPN)      // 131072
#define EPB 520452           // edges per batch
#define NE  (NB*EPB)         // 1040904 total edges
#define OUTTOT (NNODES + 3*NE)   // 3253784

// ---------------- workspace layout (float offsets) ----------------
#define H_OFF    0u
#define PS_OFF   4194304u
#define Q_OFF    8388608u
#define NF_OFF   12582912u   // float4 per node: (u, dux, dut, -)
#define WF_OFF   12845056u
#define FLAG_OFF 12922504u
#define WPK_OFF  12922508u   // 73728 ushorts = 36864 float slots (B-fragments)
#define SGB_OFF  12959372u   // 65536 floats: per-node gate sum
#define WS_NEED_FLOATS 13024908u

// f32 weight sub-offsets inside wf
#define IN_W 0
#define IN_B 64
#define MW1  128      // (3,130,64) per-layer stride 8320
#define MB1  25088    // (3,64)
#define MW2  25280    // (3,64,64) stride 4096
#define MB2  37568
#define GW1  37760    // (3,7,64) stride 448
#define GB1  39104
#define GW2  39296    // (3,64)
#define GB2  39488    // (3)
#define UW1  39492    // (3,128,64) stride 8192
#define UB1  64068
#define UW2  64260    // (3,64,64) stride 4096
#define UB2  76548
#define LNG  76740
#define LNB  76932
#define OUTW 77124
#define OUTB 77188
// folded layer-0 vectors: P = u*PA+PB, Q = u*PC+PD
#define PA   77192
#define PB   77256
#define PC   77320
#define PD   77384

typedef __hip_bfloat16 bf16;
typedef __attribute__((ext_vector_type(8))) short short8v;
typedef __attribute__((ext_vector_type(4))) float f32x4;

__device__ __forceinline__ float b2f(bf16 x){ return __bfloat162float(x); }

__device__ __forceinline__ unsigned short f2bf(float x){
  unsigned u = __float_as_uint(x);
  unsigned r = (u + 0x7fffu + ((u>>16)&1u)) >> 16;   // RNE
  return (unsigned short)r;
}

__device__ __forceinline__ float fexp2(float x){
#if __has_builtin(__builtin_amdgcn_exp2f)
  return __builtin_amdgcn_exp2f(x);
#else
  return exp2f(x);
#endif
}
__device__ __forceinline__ float frcp(float x){
#if __has_builtin(__builtin_amdgcn_rcpf)
  return __builtin_amdgcn_rcpf(x);
#else
  return 1.0f/x;
#endif
}
__device__ __forceinline__ float frsq(float x){
#if __has_builtin(__builtin_amdgcn_rsqf)
  return __builtin_amdgcn_rsqf(x);
#else
  return rsqrtf(x);
#endif
}
// tanh-approx GELU, exp2-folded
__device__ __forceinline__ float gelu_t(float v){
  float vv = v*v;
  float w  = v*fmaf(vv, 0.1029445f, 2.3022080f);
  float r  = frcp(1.0f + fexp2(w));
  return fmaf(-v, r, v);
}
__device__ __forceinline__ float sigm(float x){
  return frcp(1.0f + fexp2(-1.44269504f*x));
}
// DPP-fused add: x + dpp_perm(x)
template<int CTRL>
__device__ __forceinline__ float dppadd(float x){
  int y = __builtin_amdgcn_update_dpp(0, __float_as_int(x), CTRL, 0xf, 0xf, true);
  return x + __int_as_float(y);
}
__device__ __forceinline__ float rdlane(float x, int k){
  return __int_as_float(__builtin_amdgcn_readlane(__float_as_int(x), k));
}
// dtype-agnostic input load / output store (isf: 1 = float32, 0 = bf16)
__device__ __forceinline__ float ldf(const void* p, long i, int isf){
  return isf ? ((const float*)p)[i] : b2f(((const bf16*)p)[i]);
}
__device__ __forceinline__ void stf(void* p, long i, float v, int isf){
  if (isf) ((float*)p)[i] = v;
  else ((bf16*)p)[i] = __float2bfloat16(v);
}

// ---------------- dtype sniff ----------------
__global__ void k_sniff(const void* __restrict__ u, int* __restrict__ flag)
{
  int tid = threadIdx.x;
  unsigned w = ((const unsigned*)u)[tid];
  int bad = 0;
  #pragma unroll
  for (int h=0; h<2; h++){
    unsigned bits = ((h ? (w>>16) : (w & 0xffffu)) << 16);
    float v = __uint_as_float(bits);
    if (!(v == v) || fabsf(v) > 64.0f) bad = 1;
  }
  unsigned long long anybad = __ballot(bad);
  if (tid == 0) *flag = (anybad != 0ull) ? 1 : 0;
}

// ---------------- diagnostic fallback ----------------
__global__ void __launch_bounds__(256) k_encode(bf16* __restrict__ out, float val)
{
  int i = blockIdx.x*256 + threadIdx.x;
  if (i < OUTTOT) out[i] = __float2bfloat16(i == 0 ? val : 0.0f);
}

// ---------------- convert all weights to f32 scratch ----------------
struct WArgs { const void* p[18]; int cnt[18]; int off[18]; };

__global__ void __launch_bounds__(256) k_conv(WArgs a, float* __restrict__ wf,
                                              const int* __restrict__ flag)
{
  int y = blockIdx.y;
  int i = blockIdx.x*256 + threadIdx.x;
  int isf = *flag;
  if (i < a.cnt[y]) wf[a.off[y] + i] = ldf(a.p[y], i, isf);
}

// ---------------- fold layer-0 rank-1 vectors ----------------
__global__ void k_prep(float* __restrict__ wf)
{
  int c = threadIdx.x;   // 64 threads
  float a=0.f, b=0.f, cc=0.f, d=0.f;
  for (int j=0;j<64;j++){
    float iw = wf[IN_W+j], ib = wf[IN_B+j];
    float wp = wf[MW1 + j*64 + c];
    float wq = wf[MW1 + (64+j)*64 + c];
    a  = fmaf(iw, wp, a);  b = fmaf(ib, wp, b);
    cc = fmaf(iw, wq, cc); d = fmaf(ib, wq, d);
  }
  wf[PA+c]=a; wf[PB+c]=b; wf[PC+c]=cc; wf[PD+c]=d;
}

// ---------------- pack weights into MFMA B-fragment order (bf16) -------------
__global__ void __launch_bounds__(256) k_pack(const float* __restrict__ wf,
                                              unsigned short* __restrict__ wpk)
{
  int idx = blockIdx.x*256 + threadIdx.x;
  if (idx >= 73728) return;
  int i  = idx & 7;
  int l  = (idx >> 3) & 63;
  int ks = (idx >> 9) & 1;
  int n  = (idx >> 10) & 3;
  int mm = idx >> 12;          // 0..17
  int L = mm / 6, m = mm % 6;
  int k = ks*32 + 8*(l>>4) + i;
  int c = n*16 + (l&15);
  float v = 0.f;
  if      (m == 0) v = wf[MW2 + L*4096 + k*64 + c];
  else if (m == 1) v = wf[UW1 + L*8192 + k*64 + c];
  else if (m == 2) v = wf[UW1 + L*8192 + (64+k)*64 + c];
  else if (m == 3) v = wf[UW2 + L*4096 + k*64 + c];
  else if (m == 4) v = (L < 2) ? wf[MW1 + (L+1)*8320 + k*64 + c] : 0.f;
  else             v = (L < 2) ? wf[MW1 + (L+1)*8320 + (64+k)*64 + c] : 0.f;
  wpk[idx] = f2bf(v);
}

// ---------------- node features: nf = (u, du/dx, du/dt, 0) ----------------
__global__ void __launch_bounds__(256) k_feat(
    const void* __restrict__ ub, long ubase, const int* __restrict__ flag,
    float4* __restrict__ nf)
{
  int i = blockIdx.x*256 + threadIdx.x;   // [0, NPN)
  int isf = *flag;
  int t = i >> 9, n = i & 511;
  float uc = ldf(ub, ubase + i, isf);
  float dxv;
  if (n == 0)          dxv = (ldf(ub, ubase + t*NXX + 1, isf) - uc) * 512.0f;
  else if (n == NXX-1) dxv = (uc - ldf(ub, ubase + t*NXX + NXX-2, isf)) * 512.0f;
  else                 dxv = (ldf(ub, ubase + t*NXX + n+1, isf) - ldf(ub, ubase + t*NXX + n-1, isf)) * 256.0f;
  float dtv;
  if (t == 0)          dtv = (ldf(ub, ubase + NXX + n, isf) - uc) * 128.0f;
  else if (t == NTT-1) dtv = (uc - ldf(ub, ubase + (NTT-2)*NXX + n, isf)) * 128.0f;
  else                 dtv = (ldf(ub, ubase + (t+1)*NXX + n, isf) - ldf(ub, ubase + (t-1)*NXX + n, isf)) * 64.0f;
  nf[i] = make_float4(uc, dxv, dtv, 0.0f);
}

// ---------------- phase B v5: lane-gathered neighbors, pinned load hoist ------
template<int FIRST>
__global__ void __launch_bounds__(256) k_B(
    float* __restrict__ PS, const float* __restrict__ Qb,
    const float4* __restrict__ nf, float* __restrict__ sgb,
    const float* __restrict__ wf, int l,
    void* __restrict__ dout, long gbase, const int* __restrict__ flag)
{
  constexpr int DELTA[8] = {512,-512,1,-1,513,511,-511,-513};
  constexpr int BASEa[8] = {0,65024,130048,195456,260864,325761,390658,455555};
  constexpr int TLOa[8]  = {1,0,0,0,1,1,0,0};
  constexpr int NLOa[8]  = {0,0,1,0,1,0,1,0};
  constexpr int NCNa[8]  = {512,512,511,511,511,511,511,511};
  constexpr int DTKa[8]  = {-1,1,0,0,-1,-1,1,1};
  constexpr int DNKa[8]  = {0,0,-1,1,-1,1,-1,1};

  int lane = threadIdx.x & 63;
  int iu = __builtin_amdgcn_readfirstlane(blockIdx.x*4 + (threadIdx.x >> 6));
  int isf = *flag;
  int tu = iu >> 9, nu = iu & 511;

  const float* gw1 = wf + GW1 + l*448;
  float4 fi = nf[iu];
  float Pi, qA = 0.f, qB = 0.f;
  if (FIRST){
    Pi = fmaf(fi.x, wf[PA+lane], wf[PB+lane]);
    qA = wf[PC+lane]; qB = wf[PD+lane];
  } else {
    Pi = PS[(size_t)iu*64 + lane];
  }
  float g1 = gw1[64+lane], g2 = gw1[128+lane];
  float g4 = gw1[256+lane], g6 = gw1[384+lane];
  float a_i = wf[GB1 + l*64 + lane];
  a_i = fmaf(fi.x, gw1[lane],     a_i);
  a_i = fmaf(fi.y, gw1[192+lane], a_i);
  a_i = fmaf(fi.z, gw1[320+lane], a_i);
  float gw2v = wf[GW2 + l*64 + lane];
  float gb2v = wf[GB2 + l];
  const float* w1l = wf + MW1 + l*8320;
  float ecA = w1l[8192+lane] * (1.0f/512.0f);
  float ecB = w1l[8256+lane] * (1.0f/128.0f);
  float baseP = Pi + wf[MB1 + l*64 + lane];
  float bpA0 = baseP - ecA, bpA1 = baseP + ecA;
  float bp[8];
  bp[0]=baseP-ecB; bp[1]=baseP+ecB; bp[2]=bpA0;     bp[3]=bpA1;
  bp[4]=bpA0-ecB;  bp[5]=bpA1-ecB;  bp[6]=bpA0+ecB; bp[7]=bpA1+ecB;

  bool interior = (tu>=1) && (tu<=NTT-2) && (nu>=1) && (nu<=NXX-2);

  if (interior){
    // ---- phase 0: issue all 8 Qj loads; pin them above the gelus ----
    float qj[8];
    if (!FIRST){
      #pragma unroll
      for (int k=0;k<8;k++)
        qj[k] = Qb[(size_t)(iu + DELTA[k])*64 + lane];
      __builtin_amdgcn_sched_barrier(0);   // loads stay issued here
    }
    // ---- neighbor gather: lanes 0-7 load nf[iu+DELTA[lane]] in ONE vmem ----
    int d01 = (lane&1) ? -512 : 512;
    int d23 = (lane&1) ? -1   : 1;
    int d45 = (lane&1) ? 511  : 513;
    int d67 = (lane&1) ? -513 : -511;
    int d03 = (lane&2) ? d23 : d01;
    int d47 = (lane&2) ? d67 : d45;
    int dlt = (lane&4) ? d47 : d03;
    float4 fjL = make_float4(0.f,0.f,0.f,0.f);
    if (lane < 8) fjL = nf[iu + dlt];
    float dL = fabsf(fi.x - fjL.x);
    __builtin_amdgcn_sched_barrier(0);

    // ---- phase 1: gate-hidden gelus (neighbor scalars via readlane->SGPR) ---
    float z[8];
    float fjx[8];
    #pragma unroll
    for (int k=0;k<8;k++){
      fjx[k]    = rdlane(fjL.x, k);
      float fy  = rdlane(fjL.y, k);
      float fz  = rdlane(fjL.z, k);
      float dk  = rdlane(dL,    k);
      float hg = fmaf(fjx[k], g1, a_i);
      hg = fmaf(fy, g4, hg);
      hg = fmaf(fz, g6, hg);
      hg = fmaf(dk, g2, hg);
      z[k] = gelu_t(hg) * gw2v;
    }
    if (FIRST){
      #pragma unroll
      for (int k=0;k<8;k++) qj[k] = fmaf(fjx[k], qA, qB);
    }
    // ---- phase 2: 64-lane sum per edge (DPP + swizzle levels) ----
    #pragma unroll
    for (int k=0;k<8;k++){
      z[k] = dppadd<177>(z[k]);      // quad_perm [1,0,3,2]
      z[k] = dppadd<78>(z[k]);       // quad_perm [2,3,0,1]
      z[k] = dppadd<0x141>(z[k]);    // row_half_mirror
      z[k] = dppadd<0x140>(z[k]);    // row_mirror
      z[k] += __shfl_xor(z[k], 16);
      z[k] += __shfl_xor(z[k], 32);
    }
    // ---- phase 3: one sigmoid per lane, lane&7 selection ----
    int k7 = lane & 7;
    float s01=(k7&1)?z[1]:z[0], s23=(k7&1)?z[3]:z[2];
    float s45=(k7&1)?z[5]:z[4], s67=(k7&1)?z[7]:z[6];
    float s03=(k7&2)?s23:s01,   s47=(k7&2)?s67:s45;
    float sel=(k7&4)?s47:s03;
    float sg = sigm(sel + gb2v);     // lane holds gate for edge lane&7

    // ---- phase 4: messages (qj long since landed) ----
    float Sacc = 0.f;
    #pragma unroll
    for (int k=0;k<8;k++){
      float sk = rdlane(sg, k);
      Sacc = fmaf(sk, gelu_t(qj[k] + bp[k]), Sacc);
    }
    PS[(size_t)iu*64 + lane] = Sacc;

    // sga: 3-level DPP sum over each aligned 8-lane group
    float sga = sg;
    sga = dppadd<177>(sga);
    sga = dppadd<78>(sga);
    sga = dppadd<0x141>(sga);
    if (lane == 0) sgb[iu] = sga;

    // all 8 gate stores in one shot from lanes 0-7 (closed-form interior eids)
    int E511 = tu*511 + nu;
    int c01=(k7&1)?64512:0,      c23=(k7&1)?195455:130048;
    int c45=(k7&1)?325760:260864, c67=(k7&1)?455043:390147;
    int c03=(k7&2)?c23:c01,      c47=(k7&2)?c67:c45;
    int cc =(k7&4)?c47:c03;
    long eid = gbase + cc + ((k7<2) ? iu : E511);
    if (lane < 8) stf(dout, eid, sg, isf);
  } else {
    // ---- boundary path (~2% of nodes): checked per edge ----
    bool vT0 = (tu >= 1), vT1 = (tu <= NTT-2);
    bool vN0 = (nu >= 1), vN1 = (nu <= NXX-2);
    bool val[8] = { vT1, vT0, vN1, vN0, vT1&&vN1, vT1&&vN0, vT0&&vN1, vT0&&vN0 };
    int vidx = iu*64 + lane;
    float gg[8], m[8];
    #pragma unroll
    for (int k=0;k<8;k++){ gg[k]=0.f; m[k]=0.f; }
    #pragma unroll
    for (int k=0;k<8;k++){
      if (val[k]){
        float4 fj = nf[iu + DELTA[k]];
        float Qj = FIRST ? fmaf(fj.x, qA, qB) : (Qb + DELTA[k]*64)[vidx];
        float hg = fmaf(fj.x, g1, a_i);
        hg = fmaf(fj.y, g4, hg);
        hg = fmaf(fj.z, g6, hg);
        hg = fmaf(fabsf(fi.x - fj.x), g2, hg);
        gg[k] = gelu_t(hg) * gw2v;
        m[k]  = gelu_t(Qj + bp[k]);
      }
    }
    #pragma unroll
    for (int o=32;o;o>>=1){
      #pragma unroll
      for (int k=0;k<8;k++) gg[k] += __shfl_xor(gg[k], o);
    }
    float s01=(lane&1)?gg[1]:gg[0], s23=(lane&1)?gg[3]:gg[2];
    float s45=(lane&1)?gg[5]:gg[4], s67=(lane&1)?gg[7]:gg[6];
    float s03=(lane&2)?s23:s01, s47=(lane&2)?s67:s45;
    float sel=(lane&4)?s47:s03;
    float sg = sigm(sel + gb2v);
    float gk[8];
    #pragma unroll
    for (int k=0;k<8;k++) gk[k] = __shfl(sg, k);
    float Sacc = 0.f, sga = 0.f;
    #pragma unroll
    for (int k=0;k<8;k++){
      if (val[k]){ Sacc = fmaf(gk[k], m[k], Sacc); sga += gk[k]; }
    }
    PS[(size_t)iu*64 + lane] = Sacc;
    if (lane == 0){
      #pragma unroll
      for (int k=0;k<8;k++){
        if (val[k]){
          int ts = tu - DTKa[k], ns = nu - DNKa[k];
          long eid = gbase + BASEa[k] + (ts - TLOa[k])*NCNa[k] + (ns - NLOa[k]);
          stf(dout, eid, gk[k], isf);
        }
      }
      sgb[iu] = sga;
    }
  }
}

// ---------------- k_C v5: MFMA node GEMMs, wave-private, barrier-free ---------
template<int FIRST, int LAST>
__global__ void __launch_bounds__(256) k_C(
    float* __restrict__ PS, float* __restrict__ hbuf, float* __restrict__ Qb,
    const float4* __restrict__ nf, const float* __restrict__ sgb,
    const float* __restrict__ wf, const unsigned short* __restrict__ wpkL, int ly,
    void* __restrict__ dout, long obase, const int* __restrict__ flag)
{
  __shared__ unsigned short xb[2][64][72];
  int tid  = threadIdx.x;
  int lane = tid & 63;
  int w    = tid >> 6;
  int q    = lane >> 4;          // 0..3
  int r15  = lane & 15;
  int mbase = w*16;
  int blk = blockIdx.x;

  // ---- stage (wave-private rows): xb[0]=S bf16, xb[1]=h bf16 ----
  {
    const float4* PS4 = (const float4*)PS;
    const float4* H4  = (const float4*)hbuf;
    #pragma unroll
    for (int p=0;p<4;p++){
      int i  = lane + 64*p;
      int rr = i >> 4;
      int fc = i & 15;
      int node = blk*64 + mbase + rr;
      float4 sv = PS4[(size_t)node*16 + fc];
      uint2 spk;
      spk.x = ((unsigned)f2bf(sv.y)<<16) | f2bf(sv.x);
      spk.y = ((unsigned)f2bf(sv.w)<<16) | f2bf(sv.z);
      *(uint2*)&xb[0][mbase+rr][fc*4] = spk;
      float4 hv;
      if (FIRST){
        float uu = nf[node].x;
        hv.x = fmaf(uu, wf[IN_W+fc*4+0], wf[IN_B+fc*4+0]);
        hv.y = fmaf(uu, wf[IN_W+fc*4+1], wf[IN_B+fc*4+1]);
        hv.z = fmaf(uu, wf[IN_W+fc*4+2], wf[IN_B+fc*4+2]);
        hv.w = fmaf(uu, wf[IN_W+fc*4+3], wf[IN_B+fc*4+3]);
      } else {
        hv = H4[(size_t)node*16 + fc];
      }
      uint2 hpk;
      hpk.x = ((unsigned)f2bf(hv.y)<<16) | f2bf(hv.x);
      hpk.y = ((unsigned)f2bf(hv.w)<<16) | f2bf(hv.z);
      *(uint2*)&xb[1][mbase+rr][fc*4] = hpk;
    }
  }
  // no barrier: every wave reads only its own rows

  int noder[4];
  #pragma unroll
  for (int reg=0;reg<4;reg++) noder[reg] = blk*64 + mbase + 4*q + reg;

#define GEMM8(SEL, MAT, ACC)                                              \
  {                                                                       \
    short8v a0 = *(const short8v*)&xb[SEL][mbase + r15][8*q];             \
    short8v a1 = *(const short8v*)&xb[SEL][mbase + r15][32 + 8*q];        \
    _Pragma("unroll")                                                     \
    for (int n_=0;n_<4;n_++){                                             \
      const short8v* bp_ = (const short8v*)(wpkL + ((MAT)*4 + n_)*1024);  \
      short8v b0 = bp_[lane];                                             \
      short8v b1 = bp_[64 + lane];                                        \
      ACC[n_] = __builtin_amdgcn_mfma_f32_16x16x32_bf16(a0,b0,ACC[n_],0,0,0); \
      ACC[n_] = __builtin_amdgcn_mfma_f32_16x16x32_bf16(a1,b1,ACC[n_],0,0,0); \
    }                                                                     \
  }

  f32x4 zz = {0.f,0.f,0.f,0.f};
  f32x4 acc[4], acc2[4];

  // ---- P0: agg = S@W2 + sg*b2 ----
  #pragma unroll
  for (int n=0;n<4;n++) acc[n] = zz;
  GEMM8(0, 0, acc)
  float sg4[4];
  #pragma unroll
  for (int reg=0;reg<4;reg++) sg4[reg] = sgb[noder[reg]];
  #pragma unroll
  for (int n=0;n<4;n++){
    float b2c = wf[MB2 + ly*64 + n*16 + r15];
    #pragma unroll
    for (int reg=0;reg<4;reg++){
      float v = acc[n][reg] + sg4[reg]*b2c;
      xb[0][mbase + 4*q + reg][n*16 + r15] = f2bf(v);
    }
  }

  // ---- P1: hid = gelu(h@U1a + agg@U1b + b1) ----
  #pragma unroll
  for (int n=0;n<4;n++) acc2[n] = zz;
  GEMM8(1, 1, acc2)
  GEMM8(0, 2, acc2)
  #pragma unroll
  for (int n=0;n<4;n++){
    float b1c = wf[UB1 + ly*64 + n*16 + r15];
    #pragma unroll
    for (int reg=0;reg<4;reg++){
      float v = gelu_t(acc2[n][reg] + b1c);
      xb[1][mbase + 4*q + reg][n*16 + r15] = f2bf(v);
    }
  }

  // ---- P2: upd = hid@U2 + b2; + residual h; LN ----
  #pragma unroll
  for (int n=0;n<4;n++) acc[n] = zz;
  GEMM8(1, 3, acc)
  float val[4][4];
  float ur[4];
  if (FIRST){
    #pragma unroll
    for (int reg=0;reg<4;reg++) ur[reg] = nf[noder[reg]].x;
  }
  #pragma unroll
  for (int n=0;n<4;n++){
    int coln = n*16 + r15;
    float u2c = wf[UB2 + ly*64 + coln];
    float iwc = 0.f, ibc = 0.f;
    if (FIRST){ iwc = wf[IN_W + coln]; ibc = wf[IN_B + coln]; }
    #pragma unroll
    for (int reg=0;reg<4;reg++){
      float hres = FIRST ? fmaf(ur[reg], iwc, ibc)
                         : hbuf[(size_t)noder[reg]*64 + coln];
      val[n][reg] = acc[n][reg] + u2c + hres;
    }
  }
  float s1[4], s2[4];
  #pragma unroll
  for (int reg=0;reg<4;reg++){
    float a = 0.f, b = 0.f;
    #pragma unroll
    for (int n=0;n<4;n++){ a += val[n][reg]; b = fmaf(val[n][reg], val[n][reg], b); }
    s1[reg] = a; s2[reg] = b;
  }
  #pragma unroll
  for (int o=1;o<16;o<<=1){
    #pragma unroll
    for (int reg=0;reg<4;reg++){
      s1[reg] += __shfl_xor(s1[reg], o);
      s2[reg] += __shfl_xor(s2[reg], o);
    }
  }
  float mean[4], inv[4];
  #pragma unroll
  for (int reg=0;reg<4;reg++){
    float mm = s1[reg]*(1.0f/64.0f);
    float vv = s2[reg]*(1.0f/64.0f) - mm*mm;
    mean[reg] = mm; inv[reg] = frsq(vv + 1e-5f);
  }
  float hp[4][4];
  #pragma unroll
  for (int n=0;n<4;n++){
    int coln = n*16 + r15;
    float gc = wf[LNG + ly*64 + coln];
    float bc = wf[LNB + ly*64 + coln];
    #pragma unroll
    for (int reg=0;reg<4;reg++)
      hp[n][reg] = (val[n][reg]-mean[reg])*inv[reg]*gc + bc;
  }

  if (LAST){
    int isf = *flag;
    float po[4];
    #pragma unroll
    for (int reg=0;reg<4;reg++){
      float a = 0.f;
      #pragma unroll
      for (int n=0;n<4;n++) a = fmaf(hp[n][reg], wf[OUTW + n*16 + r15], a);
      po[reg] = a;
    }
    #pragma unroll
    for (int o=1;o<16;o<<=1){
      #pragma unroll
      for (int reg=0;reg<4;reg++) po[reg] += __shfl_xor(po[reg], o);
    }
    float ob = wf[OUTB];
    if (r15 == 0){
      #pragma unroll
      for (int reg=0;reg<4;reg++)
        stf(dout, obase + noder[reg], po[reg] + ob, isf);
    }
  } else {
    #pragma unroll
    for (int n=0;n<4;n++){
      int coln = n*16 + r15;
      #pragma unroll
      for (int reg=0;reg<4;reg++){
        hbuf[(size_t)noder[reg]*64 + coln] = hp[n][reg];
        xb[0][mbase + 4*q + reg][coln] = f2bf(hp[n][reg]);
      }
    }
    // ---- P3: P' = h'@W1a(l+1), Q' = h'@W1b(l+1) ----
    #pragma unroll
    for (int n=0;n<4;n++){ acc[n] = zz; acc2[n] = zz; }
    GEMM8(0, 4, acc)
    GEMM8(0, 5, acc2)
    #pragma unroll
    for (int n=0;n<4;n++){
      int coln = n*16 + r15;
      #pragma unroll
      for (int reg=0;reg<4;reg++){
        PS[(size_t)noder[reg]*64 + coln] = acc[n][reg];
        Qb[(size_t)noder[reg]*64 + coln] = acc2[n][reg];
      }
    }
  }
#undef GEMM8
}

// ---------------- host launcher ----------------
extern "C" void kernel_launch(void* const* d_in, const int* in_sizes, int n_in,
                              void* d_out, int out_size, void* d_ws, size_t ws_size,
                              hipStream_t stream)
{
  if (ws_size < (size_t)WS_NEED_FLOATS * 4ull) {
    k_encode<<<(OUTTOT+255)/256, 256, 0, stream>>>((bf16*)d_out, (float)ws_size);
    return;
  }

  float* ws   = (float*)d_ws;
  float* h    = ws + H_OFF;
  float* PS   = ws + PS_OFF;
  float* Qb   = ws + Q_OFF;
  float4* nf  = (float4*)(ws + NF_OFF);
  float* wf   = ws + WF_OFF;
  int*  flag  = (int*)(ws + FLAG_OFF);
  unsigned short* wpk = (unsigned short*)(ws + WPK_OFF);
  float* sgb  = ws + SGB_OFF;

  k_sniff<<<1, 64, 0, stream>>>(d_in[1], flag);

  WArgs wa;
  static const int cnts[18] = {64,64,24960,192,12288,192,1344,192,192,3,24576,192,12288,192,192,192,64,1};
  static const int offs[18] = {IN_W,IN_B,MW1,MB1,MW2,MB2,GW1,GB1,GW2,GB2,UW1,UB1,UW2,UB2,LNG,LNB,OUTW,OUTB};
  for (int k = 0; k < 18; k++){ wa.p[k] = d_in[4+k]; wa.cnt[k] = cnts[k]; wa.off[k] = offs[k]; }
  k_conv<<<dim3(98,18), 256, 0, stream>>>(wa, wf, flag);
  k_prep<<<1, 64, 0, stream>>>(wf);
  k_pack<<<288, 256, 0, stream>>>(wf, wpk);

  for (int b = 0; b < NB; b++){
    k_feat<<<256, 256, 0, stream>>>(d_in[1], (long)b*NPN, flag, nf);

    for (int l = 0; l < 3; l++){
      long gb = (long)NNODES + (long)l*NE + (long)b*EPB;
      const unsigned short* wpkL = wpk + l*24576;
      if (l == 0)
        k_B<1><<<16384, 256, 0, stream>>>(PS, Qb, nf, sgb, wf, l, d_out, gb, flag);
      else
        k_B<0><<<16384, 256, 0, stream>>>(PS, Qb, nf, sgb, wf, l, d_out, gb, flag);

      if (l == 0)
        k_C<1,0><<<1024, 256, 0, stream>>>(PS, h, Qb, nf, sgb, wf, wpkL, l,
                                           d_out, (long)b*NPN, flag);
      else if (l == 1)
        k_C<0,0><<<1024, 256, 0, stream>>>(PS, h, Qb, nf, sgb, wf, wpkL, l,
                                           d_out, (long)b*NPN, flag);
      else
        k_C<0,1><<<1024, 256, 0, stream>>>(PS, h, Qb, nf, sgb, wf, wpkL, l,
                                           d_out, (long)b*NPN, flag);
    }
  }
}

// Round 14
// 343.105 us; speedup vs baseline: 1.1088x; 1.1088x over previous
//
#include <hip/hip_runtime.h>
#include <hip/hip_bf16.h>

// ---------------- problem constants ----------------
#define NTT 128
#define NXX 512
#define NB  2
#define NPN (NTT*NXX)        // 65536 nodes per batch
#define NNODES (NB*NPN)      // 131072
#define EPB 520452           // edges per batch
#define NE  (NB*EPB)         // 1040904 total edges
#define OUTTOT (NNODES + 3*NE)   // 3253784

// ---------------- workspace layout (float offsets) ----------------
#define H_OFF    0u
#define PS_OFF   4194304u
#define Q_OFF    8388608u
#define NF_OFF   12582912u   // float4 per node: (u, dux, dut, -)
#define WF_OFF   12845056u
#define FLAG_OFF 12922504u
#define WPK_OFF  12922508u   // 73728 ushorts = 36864 float slots (B-fragments)
#define SGB_OFF  12959372u   // 65536 floats: per-node gate sum
#define WS_NEED_FLOATS 13024908u

// f32 weight sub-offsets inside wf
#define IN_W 0
#define IN_B 64
#define MW1  128      // (3,130,64) per-layer stride 8320
#define MB1  25088    // (3,64)
#define MW2  25280    // (3,64,64) stride 4096
#define MB2  37568
#define GW1  37760    // (3,7,64) stride 448
#define GB1  39104
#define GW2  39296    // (3,64)
#define GB2  39488    // (3)
#define UW1  39492    // (3,128,64) stride 8192
#define UB1  64068
#define UW2  64260    // (3,64,64) stride 4096
#define UB2  76548
#define LNG  76740
#define LNB  76932
#define OUTW 77124
#define OUTB 77188
// folded layer-0 vectors: P = u*PA+PB, Q = u*PC+PD
#define PA   77192
#define PB   77256
#define PC   77320
#define PD   77384

typedef __hip_bfloat16 bf16;
typedef __attribute__((ext_vector_type(8))) short short8v;
typedef __attribute__((ext_vector_type(4))) float f32x4;

__device__ __forceinline__ float b2f(bf16 x){ return __bfloat162float(x); }

__device__ __forceinline__ unsigned short f2bf(float x){
  unsigned u = __float_as_uint(x);
  unsigned r = (u + 0x7fffu + ((u>>16)&1u)) >> 16;   // RNE
  return (unsigned short)r;
}

__device__ __forceinline__ float fexp2(float x){
#if __has_builtin(__builtin_amdgcn_exp2f)
  return __builtin_amdgcn_exp2f(x);
#else
  return exp2f(x);
#endif
}
__device__ __forceinline__ float frcp(float x){
#if __has_builtin(__builtin_amdgcn_rcpf)
  return __builtin_amdgcn_rcpf(x);
#else
  return 1.0f/x;
#endif
}
__device__ __forceinline__ float frsq(float x){
#if __has_builtin(__builtin_amdgcn_rsqf)
  return __builtin_amdgcn_rsqf(x);
#else
  return rsqrtf(x);
#endif
}
// tanh-approx GELU, exp2-folded
__device__ __forceinline__ float gelu_t(float v){
  float vv = v*v;
  float w  = v*fmaf(vv, 0.1029445f, 2.3022080f);
  float r  = frcp(1.0f + fexp2(w));
  return fmaf(-v, r, v);
}
__device__ __forceinline__ float sigm(float x){
  return frcp(1.0f + fexp2(-1.44269504f*x));
}
// DPP-fused add: x + dpp_perm(x)
template<int CTRL>
__device__ __forceinline__ float dppadd(float x){
  int y = __builtin_amdgcn_update_dpp(0, __float_as_int(x), CTRL, 0xf, 0xf, true);
  return x + __int_as_float(y);
}
// dtype-agnostic input load / output store (isf: 1 = float32, 0 = bf16)
__device__ __forceinline__ float ldf(const void* p, long i, int isf){
  return isf ? ((const float*)p)[i] : b2f(((const bf16*)p)[i]);
}
__device__ __forceinline__ void stf(void* p, long i, float v, int isf){
  if (isf) ((float*)p)[i] = v;
  else ((bf16*)p)[i] = __float2bfloat16(v);
}

// ---------------- dtype sniff ----------------
__global__ void k_sniff(const void* __restrict__ u, int* __restrict__ flag)
{
  int tid = threadIdx.x;
  unsigned w = ((const unsigned*)u)[tid];
  int bad = 0;
  #pragma unroll
  for (int h=0; h<2; h++){
    unsigned bits = ((h ? (w>>16) : (w & 0xffffu)) << 16);
    float v = __uint_as_float(bits);
    if (!(v == v) || fabsf(v) > 64.0f) bad = 1;
  }
  unsigned long long anybad = __ballot(bad);
  if (tid == 0) *flag = (anybad != 0ull) ? 1 : 0;
}

// ---------------- diagnostic fallback ----------------
__global__ void __launch_bounds__(256) k_encode(bf16* __restrict__ out, float val)
{
  int i = blockIdx.x*256 + threadIdx.x;
  if (i < OUTTOT) out[i] = __float2bfloat16(i == 0 ? val : 0.0f);
}

// ---------------- convert all weights to f32 scratch ----------------
struct WArgs { const void* p[18]; int cnt[18]; int off[18]; };

__global__ void __launch_bounds__(256) k_conv(WArgs a, float* __restrict__ wf,
                                              const int* __restrict__ flag)
{
  int y = blockIdx.y;
  int i = blockIdx.x*256 + threadIdx.x;
  int isf = *flag;
  if (i < a.cnt[y]) wf[a.off[y] + i] = ldf(a.p[y], i, isf);
}

// ---------------- fold layer-0 rank-1 vectors ----------------
__global__ void k_prep(float* __restrict__ wf)
{
  int c = threadIdx.x;   // 64 threads
  float a=0.f, b=0.f, cc=0.f, d=0.f;
  for (int j=0;j<64;j++){
    float iw = wf[IN_W+j], ib = wf[IN_B+j];
    float wp = wf[MW1 + j*64 + c];
    float wq = wf[MW1 + (64+j)*64 + c];
    a  = fmaf(iw, wp, a);  b = fmaf(ib, wp, b);
    cc = fmaf(iw, wq, cc); d = fmaf(ib, wq, d);
  }
  wf[PA+c]=a; wf[PB+c]=b; wf[PC+c]=cc; wf[PD+c]=d;
}

// ---------------- pack weights into MFMA B-fragment order (bf16) -------------
__global__ void __launch_bounds__(256) k_pack(const float* __restrict__ wf,
                                              unsigned short* __restrict__ wpk)
{
  int idx = blockIdx.x*256 + threadIdx.x;
  if (idx >= 73728) return;
  int i  = idx & 7;
  int l  = (idx >> 3) & 63;
  int ks = (idx >> 9) & 1;
  int n  = (idx >> 10) & 3;
  int mm = idx >> 12;          // 0..17
  int L = mm / 6, m = mm % 6;
  int k = ks*32 + 8*(l>>4) + i;
  int c = n*16 + (l&15);
  float v = 0.f;
  if      (m == 0) v = wf[MW2 + L*4096 + k*64 + c];
  else if (m == 1) v = wf[UW1 + L*8192 + k*64 + c];
  else if (m == 2) v = wf[UW1 + L*8192 + (64+k)*64 + c];
  else if (m == 3) v = wf[UW2 + L*4096 + k*64 + c];
  else if (m == 4) v = (L < 2) ? wf[MW1 + (L+1)*8320 + k*64 + c] : 0.f;
  else             v = (L < 2) ? wf[MW1 + (L+1)*8320 + (64+k)*64 + c] : 0.f;
  wpk[idx] = f2bf(v);
}

// ---------------- node features: nf = (u, du/dx, du/dt, 0) ----------------
__global__ void __launch_bounds__(256) k_feat(
    const void* __restrict__ ub, long ubase, const int* __restrict__ flag,
    float4* __restrict__ nf)
{
  int i = blockIdx.x*256 + threadIdx.x;   // [0, NPN)
  int isf = *flag;
  int t = i >> 9, n = i & 511;
  float uc = ldf(ub, ubase + i, isf);
  float dxv;
  if (n == 0)          dxv = (ldf(ub, ubase + t*NXX + 1, isf) - uc) * 512.0f;
  else if (n == NXX-1) dxv = (uc - ldf(ub, ubase + t*NXX + NXX-2, isf)) * 512.0f;
  else                 dxv = (ldf(ub, ubase + t*NXX + n+1, isf) - ldf(ub, ubase + t*NXX + n-1, isf)) * 256.0f;
  float dtv;
  if (t == 0)          dtv = (ldf(ub, ubase + NXX + n, isf) - uc) * 128.0f;
  else if (t == NTT-1) dtv = (uc - ldf(ub, ubase + (NTT-2)*NXX + n, isf)) * 128.0f;
  else                 dtv = (ldf(ub, ubase + (t+1)*NXX + n, isf) - ldf(ub, ubase + (t-1)*NXX + n, isf)) * 64.0f;
  nf[i] = make_float4(uc, dxv, dtv, 0.0f);
}

// ---------------- phase B v3: interior fast path, DPP reduce ----------------
template<int FIRST>
__global__ void __launch_bounds__(256) k_B(
    float* __restrict__ PS, const float* __restrict__ Qb,
    const float4* __restrict__ nf, float* __restrict__ sgb,
    const float* __restrict__ wf, int l,
    void* __restrict__ dout, long gbase, const int* __restrict__ flag)
{
  constexpr int DELTA[8] = {512,-512,1,-1,513,511,-511,-513};
  constexpr int BASEa[8] = {0,65024,130048,195456,260864,325761,390658,455555};
  constexpr int TLOa[8]  = {1,0,0,0,1,1,0,0};
  constexpr int NLOa[8]  = {0,0,1,0,1,0,1,0};
  constexpr int NCNa[8]  = {512,512,511,511,511,511,511,511};
  constexpr int DTKa[8]  = {-1,1,0,0,-1,-1,1,1};
  constexpr int DNKa[8]  = {0,0,-1,1,-1,1,-1,1};

  int lane = threadIdx.x & 63;
  int iu = __builtin_amdgcn_readfirstlane(blockIdx.x*4 + (threadIdx.x >> 6));
  int isf = *flag;
  int tu = iu >> 9, nu = iu & 511;

  const float* gw1 = wf + GW1 + l*448;
  float4 fi = nf[iu];
  float Pi, qA = 0.f, qB = 0.f;
  if (FIRST){
    Pi = fmaf(fi.x, wf[PA+lane], wf[PB+lane]);
    qA = wf[PC+lane]; qB = wf[PD+lane];
  } else {
    Pi = PS[(size_t)iu*64 + lane];
  }
  float g1 = gw1[64+lane], g2 = gw1[128+lane];
  float g4 = gw1[256+lane], g6 = gw1[384+lane];
  float a_i = wf[GB1 + l*64 + lane];
  a_i = fmaf(fi.x, gw1[lane],     a_i);
  a_i = fmaf(fi.y, gw1[192+lane], a_i);
  a_i = fmaf(fi.z, gw1[320+lane], a_i);
  float gw2v = wf[GW2 + l*64 + lane];
  float gb2v = wf[GB2 + l];
  const float* w1l = wf + MW1 + l*8320;
  float ecA = w1l[8192+lane] * (1.0f/512.0f);
  float ecB = w1l[8256+lane] * (1.0f/128.0f);
  float baseP = Pi + wf[MB1 + l*64 + lane];
  float bpA0 = baseP - ecA, bpA1 = baseP + ecA;
  float bp[8];
  bp[0]=baseP-ecB; bp[1]=baseP+ecB; bp[2]=bpA0;     bp[3]=bpA1;
  bp[4]=bpA0-ecB;  bp[5]=bpA1-ecB;  bp[6]=bpA0+ecB; bp[7]=bpA1+ecB;

  bool interior = (tu>=1) && (tu<=NTT-2) && (nu>=1) && (nu<=NXX-2);

  if (interior){
    // ---- fast path: no bounds checks, everything unrolled ----
    float z[8], m[8];
    #pragma unroll
    for (int k=0;k<8;k++){
      float4 fj = nf[iu + DELTA[k]];
      float Qj = FIRST ? fmaf(fj.x, qA, qB)
                       : Qb[(size_t)(iu + DELTA[k])*64 + lane];
      float d = fabsf(fi.x - fj.x);
      float hg = fmaf(fj.x, g1, a_i);
      hg = fmaf(fj.y, g4, hg);
      hg = fmaf(fj.z, g6, hg);
      hg = fmaf(d, g2, hg);
      z[k] = gelu_t(hg) * gw2v;
      m[k] = gelu_t(Qj + bp[k]);
    }
    // 64-lane sum per edge: DPP xor1, xor2, half-mirror, mirror + shfl 16, 32
    #pragma unroll
    for (int k=0;k<8;k++){
      z[k] = dppadd<177>(z[k]);      // quad_perm [1,0,3,2]
      z[k] = dppadd<78>(z[k]);       // quad_perm [2,3,0,1]
      z[k] = dppadd<0x141>(z[k]);    // row_half_mirror
      z[k] = dppadd<0x140>(z[k]);    // row_mirror
      z[k] += __shfl_xor(z[k], 16);
      z[k] += __shfl_xor(z[k], 32);
    }
    int k7 = lane & 7;
    float s01=(k7&1)?z[1]:z[0], s23=(k7&1)?z[3]:z[2];
    float s45=(k7&1)?z[5]:z[4], s67=(k7&1)?z[7]:z[6];
    float s03=(k7&2)?s23:s01,   s47=(k7&2)?s67:s45;
    float sel=(k7&4)?s47:s03;
    float sg = sigm(sel + gb2v);     // lane holds gate for edge lane&7

    // Sacc via readlane-broadcast gates
    float Sacc = 0.f;
    #pragma unroll
    for (int k=0;k<8;k++){
      float sk = __int_as_float(__builtin_amdgcn_readlane(__float_as_int(sg), k));
      Sacc = fmaf(sk, m[k], Sacc);
    }
    PS[(size_t)iu*64 + lane] = Sacc;

    // sga: 3-level DPP sum over each aligned 8-lane group
    float sga = sg;
    sga = dppadd<177>(sga);
    sga = dppadd<78>(sga);
    sga = dppadd<0x141>(sga);
    if (lane == 0) sgb[iu] = sga;

    // all 8 gate stores in one shot from lanes 0-7 (closed-form interior eids)
    int E511 = tu*511 + nu;
    int c01=(k7&1)?64512:0,      c23=(k7&1)?195455:130048;
    int c45=(k7&1)?325760:260864, c67=(k7&1)?455043:390147;
    int c03=(k7&2)?c23:c01,      c47=(k7&2)?c67:c45;
    int cc =(k7&4)?c47:c03;
    long eid = gbase + cc + ((k7<2) ? iu : E511);
    if (lane < 8) stf(dout, eid, sg, isf);
  } else {
    // ---- boundary path (~2% of nodes): checked per edge ----
    bool vT0 = (tu >= 1), vT1 = (tu <= NTT-2);
    bool vN0 = (nu >= 1), vN1 = (nu <= NXX-2);
    bool val[8] = { vT1, vT0, vN1, vN0, vT1&&vN1, vT1&&vN0, vT0&&vN1, vT0&&vN0 };
    int vidx = iu*64 + lane;
    float gg[8], m[8];
    #pragma unroll
    for (int k=0;k<8;k++){ gg[k]=0.f; m[k]=0.f; }
    #pragma unroll
    for (int k=0;k<8;k++){
      if (val[k]){
        float4 fj = nf[iu + DELTA[k]];
        float Qj = FIRST ? fmaf(fj.x, qA, qB) : (Qb + DELTA[k]*64)[vidx];
        float hg = fmaf(fj.x, g1, a_i);
        hg = fmaf(fj.y, g4, hg);
        hg = fmaf(fj.z, g6, hg);
        hg = fmaf(fabsf(fi.x - fj.x), g2, hg);
        gg[k] = gelu_t(hg) * gw2v;
        m[k]  = gelu_t(Qj + bp[k]);
      }
    }
    #pragma unroll
    for (int o=32;o;o>>=1){
      #pragma unroll
      for (int k=0;k<8;k++) gg[k] += __shfl_xor(gg[k], o);
    }
    float s01=(lane&1)?gg[1]:gg[0], s23=(lane&1)?gg[3]:gg[2];
    float s45=(lane&1)?gg[5]:gg[4], s67=(lane&1)?gg[7]:gg[6];
    float s03=(lane&2)?s23:s01, s47=(lane&2)?s67:s45;
    float sel=(lane&4)?s47:s03;
    float sg = sigm(sel + gb2v);
    float gk[8];
    #pragma unroll
    for (int k=0;k<8;k++) gk[k] = __shfl(sg, k);
    float Sacc = 0.f, sga = 0.f;
    #pragma unroll
    for (int k=0;k<8;k++){
      if (val[k]){ Sacc = fmaf(gk[k], m[k], Sacc); sga += gk[k]; }
    }
    PS[(size_t)iu*64 + lane] = Sacc;
    if (lane == 0){
      #pragma unroll
      for (int k=0;k<8;k++){
        if (val[k]){
          int ts = tu - DTKa[k], ns = nu - DNKa[k];
          long eid = gbase + BASEa[k] + (ts - TLOa[k])*NCNa[k] + (ns - NLOa[k]);
          stf(dout, eid, gk[k], isf);
        }
      }
      sgb[iu] = sga;
    }
  }
}

// ---------------- k_C v5: MFMA node GEMMs, wave-private, barrier-free ---------
template<int FIRST, int LAST>
__global__ void __launch_bounds__(256) k_C(
    float* __restrict__ PS, float* __restrict__ hbuf, float* __restrict__ Qb,
    const float4* __restrict__ nf, const float* __restrict__ sgb,
    const float* __restrict__ wf, const unsigned short* __restrict__ wpkL, int ly,
    void* __restrict__ dout, long obase, const int* __restrict__ flag)
{
  __shared__ unsigned short xb[2][64][72];
  int tid  = threadIdx.x;
  int lane = tid & 63;
  int w    = tid >> 6;
  int q    = lane >> 4;          // 0..3
  int r15  = lane & 15;
  int mbase = w*16;
  int blk = blockIdx.x;

  // ---- stage (wave-private rows): xb[0]=S bf16, xb[1]=h bf16 ----
  {
    const float4* PS4 = (const float4*)PS;
    const float4* H4  = (const float4*)hbuf;
    #pragma unroll
    for (int p=0;p<4;p++){
      int i  = lane + 64*p;
      int rr = i >> 4;
      int fc = i & 15;
      int node = blk*64 + mbase + rr;
      float4 sv = PS4[(size_t)node*16 + fc];
      uint2 spk;
      spk.x = ((unsigned)f2bf(sv.y)<<16) | f2bf(sv.x);
      spk.y = ((unsigned)f2bf(sv.w)<<16) | f2bf(sv.z);
      *(uint2*)&xb[0][mbase+rr][fc*4] = spk;
      float4 hv;
      if (FIRST){
        float uu = nf[node].x;
        hv.x = fmaf(uu, wf[IN_W+fc*4+0], wf[IN_B+fc*4+0]);
        hv.y = fmaf(uu, wf[IN_W+fc*4+1], wf[IN_B+fc*4+1]);
        hv.z = fmaf(uu, wf[IN_W+fc*4+2], wf[IN_B+fc*4+2]);
        hv.w = fmaf(uu, wf[IN_W+fc*4+3], wf[IN_B+fc*4+3]);
      } else {
        hv = H4[(size_t)node*16 + fc];
      }
      uint2 hpk;
      hpk.x = ((unsigned)f2bf(hv.y)<<16) | f2bf(hv.x);
      hpk.y = ((unsigned)f2bf(hv.w)<<16) | f2bf(hv.z);
      *(uint2*)&xb[1][mbase+rr][fc*4] = hpk;
    }
  }
  // no barrier: every wave reads only its own rows

  int noder[4];
  #pragma unroll
  for (int reg=0;reg<4;reg++) noder[reg] = blk*64 + mbase + 4*q + reg;

#define GEMM8(SEL, MAT, ACC)                                              \
  {                                                                       \
    short8v a0 = *(const short8v*)&xb[SEL][mbase + r15][8*q];             \
    short8v a1 = *(const short8v*)&xb[SEL][mbase + r15][32 + 8*q];        \
    _Pragma("unroll")                                                     \
    for (int n_=0;n_<4;n_++){                                             \
      const short8v* bp_ = (const short8v*)(wpkL + ((MAT)*4 + n_)*1024);  \
      short8v b0 = bp_[lane];                                             \
      short8v b1 = bp_[64 + lane];                                        \
      ACC[n_] = __builtin_amdgcn_mfma_f32_16x16x32_bf16(a0,b0,ACC[n_],0,0,0); \
      ACC[n_] = __builtin_amdgcn_mfma_f32_16x16x32_bf16(a1,b1,ACC[n_],0,0,0); \
    }                                                                     \
  }

  f32x4 zz = {0.f,0.f,0.f,0.f};
  f32x4 acc[4], acc2[4];

  // ---- P0: agg = S@W2 + sg*b2 ----
  #pragma unroll
  for (int n=0;n<4;n++) acc[n] = zz;
  GEMM8(0, 0, acc)
  float sg4[4];
  #pragma unroll
  for (int reg=0;reg<4;reg++) sg4[reg] = sgb[noder[reg]];
  #pragma unroll
  for (int n=0;n<4;n++){
    float b2c = wf[MB2 + ly*64 + n*16 + r15];
    #pragma unroll
    for (int reg=0;reg<4;reg++){
      float v = acc[n][reg] + sg4[reg]*b2c;
      xb[0][mbase + 4*q + reg][n*16 + r15] = f2bf(v);
    }
  }

  // ---- P1: hid = gelu(h@U1a + agg@U1b + b1) ----
  #pragma unroll
  for (int n=0;n<4;n++) acc2[n] = zz;
  GEMM8(1, 1, acc2)
  GEMM8(0, 2, acc2)
  #pragma unroll
  for (int n=0;n<4;n++){
    float b1c = wf[UB1 + ly*64 + n*16 + r15];
    #pragma unroll
    for (int reg=0;reg<4;reg++){
      float v = gelu_t(acc2[n][reg] + b1c);
      xb[1][mbase + 4*q + reg][n*16 + r15] = f2bf(v);
    }
  }

  // ---- P2: upd = hid@U2 + b2; + residual h; LN ----
  #pragma unroll
  for (int n=0;n<4;n++) acc[n] = zz;
  GEMM8(1, 3, acc)
  float val[4][4];
  float ur[4];
  if (FIRST){
    #pragma unroll
    for (int reg=0;reg<4;reg++) ur[reg] = nf[noder[reg]].x;
  }
  #pragma unroll
  for (int n=0;n<4;n++){
    int coln = n*16 + r15;
    float u2c = wf[UB2 + ly*64 + coln];
    float iwc = 0.f, ibc = 0.f;
    if (FIRST){ iwc = wf[IN_W + coln]; ibc = wf[IN_B + coln]; }
    #pragma unroll
    for (int reg=0;reg<4;reg++){
      float hres = FIRST ? fmaf(ur[reg], iwc, ibc)
                         : hbuf[(size_t)noder[reg]*64 + coln];
      val[n][reg] = acc[n][reg] + u2c + hres;
    }
  }
  float s1[4], s2[4];
  #pragma unroll
  for (int reg=0;reg<4;reg++){
    float a = 0.f, b = 0.f;
    #pragma unroll
    for (int n=0;n<4;n++){ a += val[n][reg]; b = fmaf(val[n][reg], val[n][reg], b); }
    s1[reg] = a; s2[reg] = b;
  }
  #pragma unroll
  for (int o=1;o<16;o<<=1){
    #pragma unroll
    for (int reg=0;reg<4;reg++){
      s1[reg] += __shfl_xor(s1[reg], o);
      s2[reg] += __shfl_xor(s2[reg], o);
    }
  }
  float mean[4], inv[4];
  #pragma unroll
  for (int reg=0;reg<4;reg++){
    float mm = s1[reg]*(1.0f/64.0f);
    float vv = s2[reg]*(1.0f/64.0f) - mm*mm;
    mean[reg] = mm; inv[reg] = frsq(vv + 1e-5f);
  }
  float hp[4][4];
  #pragma unroll
  for (int n=0;n<4;n++){
    int coln = n*16 + r15;
    float gc = wf[LNG + ly*64 + coln];
    float bc = wf[LNB + ly*64 + coln];
    #pragma unroll
    for (int reg=0;reg<4;reg++)
      hp[n][reg] = (val[n][reg]-mean[reg])*inv[reg]*gc + bc;
  }

  if (LAST){
    int isf = *flag;
    float po[4];
    #pragma unroll
    for (int reg=0;reg<4;reg++){
      float a = 0.f;
      #pragma unroll
      for (int n=0;n<4;n++) a = fmaf(hp[n][reg], wf[OUTW + n*16 + r15], a);
      po[reg] = a;
    }
    #pragma unroll
    for (int o=1;o<16;o<<=1){
      #pragma unroll
      for (int reg=0;reg<4;reg++) po[reg] += __shfl_xor(po[reg], o);
    }
    float ob = wf[OUTB];
    if (r15 == 0){
      #pragma unroll
      for (int reg=0;reg<4;reg++)
        stf(dout, obase + noder[reg], po[reg] + ob, isf);
    }
  } else {
    #pragma unroll
    for (int n=0;n<4;n++){
      int coln = n*16 + r15;
      #pragma unroll
      for (int reg=0;reg<4;reg++){
        hbuf[(size_t)noder[reg]*64 + coln] = hp[n][reg];
        xb[0][mbase + 4*q + reg][coln] = f2bf(hp[n][reg]);
      }
    }
    // ---- P3: P' = h'@W1a(l+1), Q' = h'@W1b(l+1) ----
    #pragma unroll
    for (int n=0;n<4;n++){ acc[n] = zz; acc2[n] = zz; }
    GEMM8(0, 4, acc)
    GEMM8(0, 5, acc2)
    #pragma unroll
    for (int n=0;n<4;n++){
      int coln = n*16 + r15;
      #pragma unroll
      for (int reg=0;reg<4;reg++){
        PS[(size_t)noder[reg]*64 + coln] = acc[n][reg];
        Qb[(size_t)noder[reg]*64 + coln] = acc2[n][reg];
      }
    }
  }
#undef GEMM8
}

// ---------------- host launcher ----------------
extern "C" void kernel_launch(void* const* d_in, const int* in_sizes, int n_in,
                              void* d_out, int out_size, void* d_ws, size_t ws_size,
                              hipStream_t stream)
{
  if (ws_size < (size_t)WS_NEED_FLOATS * 4ull) {
    k_encode<<<(OUTTOT+255)/256, 256, 0, stream>>>((bf16*)d_out, (float)ws_size);
    return;
  }

  float* ws   = (float*)d_ws;
  float* h    = ws + H_OFF;
  float* PS   = ws + PS_OFF;
  float* Qb   = ws + Q_OFF;
  float4* nf  = (float4*)(ws + NF_OFF);
  float* wf   = ws + WF_OFF;
  int*  flag  = (int*)(ws + FLAG_OFF);
  unsigned short* wpk = (unsigned short*)(ws + WPK_OFF);
  float* sgb  = ws + SGB_OFF;

  k_sniff<<<1, 64, 0, stream>>>(d_in[1], flag);

  WArgs wa;
  static const int cnts[18] = {64,64,24960,192,12288,192,1344,192,192,3,24576,192,12288,192,192,192,64,1};
  static const int offs[18] = {IN_W,IN_B,MW1,MB1,MW2,MB2,GW1,GB1,GW2,GB2,UW1,UB1,UW2,UB2,LNG,LNB,OUTW,OUTB};
  for (int k = 0; k < 18; k++){ wa.p[k] = d_in[4+k]; wa.cnt[k] = cnts[k]; wa.off[k] = offs[k]; }
  k_conv<<<dim3(98,18), 256, 0, stream>>>(wa, wf, flag);
  k_prep<<<1, 64, 0, stream>>>(wf);
  k_pack<<<288, 256, 0, stream>>>(wf, wpk);

  for (int b = 0; b < NB; b++){
    k_feat<<<256, 256, 0, stream>>>(d_in[1], (long)b*NPN, flag, nf);

    for (int l = 0; l < 3; l++){
      long gb = (long)NNODES + (long)l*NE + (long)b*EPB;
      const unsigned short* wpkL = wpk + l*24576;
      if (l == 0)
        k_B<1><<<16384, 256, 0, stream>>>(PS, Qb, nf, sgb, wf, l, d_out, gb, flag);
      else
        k_B<0><<<16384, 256, 0, stream>>>(PS, Qb, nf, sgb, wf, l, d_out, gb, flag);

      if (l == 0)
        k_C<1,0><<<1024, 256, 0, stream>>>(PS, h, Qb, nf, sgb, wf, wpkL, l,
                                           d_out, (long)b*NPN, flag);
      else if (l == 1)
        k_C<0,0><<<1024, 256, 0, stream>>>(PS, h, Qb, nf, sgb, wf, wpkL, l,
                                           d_out, (long)b*NPN, flag);
      else
        k_C<0,1><<<1024, 256, 0, stream>>>(PS, h, Qb, nf, sgb, wf, wpkL, l,
                                           d_out, (long)b*NPN, flag);
    }
  }
}